// Round 8
// baseline (1321.139 us; speedup 1.0000x reference)
//
#include <hip/hip_runtime.h>
#include <hip/hip_bf16.h>
#include <cstddef>

// ResCapsNet forward, round 8.
// - pcaps_k: 512 threads (co x 4 ci-quarters) + LDS partial reduction.
//   r7 analysis: register-row form was still latency-bound at 2.25 waves/SIMD
//   (VALUBusy 26%). Same inner loop (ILP preserved), 4x the waves.
// - Everything else unchanged from round 7 (passed, absmax 0.0039, 1094 us).
//
// ws layout (fp32-H mode, needs 223,283,200 B; bf16-H fallback if smaller):
//   X @ 0 (26,214,400 fl) | H @ 26,214,400 | tail:
//   WT 331,776 | PART 32,768 (unused) | SB 512 | P 1,327,104 | BLOG 1,658,880 | S | V
//   Overlays: trunk: W1T+WA3 in P, PARTC in BLOG; routing: SPART in P (dead post-uhat).

#define B_ 128
#define HW_ 80
#define PIX 6400
#define CHW 204800
#define NPRIM 1296

typedef __attribute__((ext_vector_type(8))) short bf16x8;
typedef __attribute__((ext_vector_type(4))) float f32x4;

// ---- H storage helpers (fp32 or bf16) ----
__device__ inline float ldH(const float* p, size_t i) { return p[i]; }
__device__ inline float ldH(const unsigned short* p, size_t i) {
  union { unsigned int u; float f; } c; c.u = ((unsigned int)p[i]) << 16; return c.f;
}
__device__ inline void stH(float* p, size_t i, float v) { p[i] = v; }
__device__ inline void stH(unsigned short* p, size_t i, float v) {
  __hip_bfloat16 b = __float2bfloat16(v);
  p[i] = *reinterpret_cast<unsigned short*>(&b);
}
__device__ inline float bf16tof(unsigned short u) {
  union { unsigned int uu; float f; } c; c.uu = ((unsigned int)u) << 16; return c.f;
}
__device__ inline unsigned short ftobf16(float v) {
  __hip_bfloat16 b = __float2bfloat16(v);
  return *reinterpret_cast<unsigned short*>(&b);
}
// load 4 consecutive H values into float regs
__device__ inline void ld4H(const float* p, size_t i, float* o) {
  float4 v = *reinterpret_cast<const float4*>(p + i);
  o[0] = v.x; o[1] = v.y; o[2] = v.z; o[3] = v.w;
}
__device__ inline void ld4H(const unsigned short* p, size_t i, float* o) {
  ushort4 v = *reinterpret_cast<const ushort4*>(p + i);
  o[0] = bf16tof(v.x); o[1] = bf16tof(v.y); o[2] = bf16tof(v.z); o[3] = bf16tof(v.w);
}

// ---------------- conv1: 1->32, k3 s1 p1, + bias -> X raw; fused stats ----------------
__global__ __launch_bounds__(256) void conv1_k(const float* __restrict__ x,
                                               const float* __restrict__ w,
                                               const float* __restrict__ bias,
                                               float* __restrict__ out,
                                               float* __restrict__ partc) {
  __shared__ float sAB[4 * 64];
  int idx = blockIdx.x * 256 + threadIdx.x;      // 819200
  int b = idx / PIX, p = idx - b * PIX;
  int y = p / HW_, xx = p - y * HW_;
  const float* xb = x + (size_t)b * PIX;
  float in[3][3];
#pragma unroll
  for (int dy = 0; dy < 3; dy++) {
    int yy = y + dy - 1;
#pragma unroll
    for (int dx = 0; dx < 3; dx++) {
      int xc = xx + dx - 1;
      in[dy][dx] = (yy >= 0 && yy < HW_ && xc >= 0 && xc < HW_) ? xb[yy * HW_ + xc] : 0.f;
    }
  }
  int lane = threadIdx.x & 63, wv = threadIdx.x >> 6;
  size_t obase = (size_t)b * CHW + p;
#pragma unroll 1
  for (int co = 0; co < 32; co++) {
    float a = bias[co];
#pragma unroll
    for (int t = 0; t < 9; t++) a = fmaf(in[t / 3][t % 3], w[co * 9 + t], a);
    out[obase + (size_t)co * PIX] = a;
    float r = a, r2 = a * a;
#pragma unroll
    for (int off = 32; off > 0; off >>= 1) { r += __shfl_down(r, off); r2 += __shfl_down(r2, off); }
    if (lane == 0) { sAB[wv * 64 + co] = r; sAB[wv * 64 + 32 + co] = r2; }
  }
  __syncthreads();
  if (threadIdx.x < 64) {
    float s = sAB[threadIdx.x] + sAB[64 + threadIdx.x] + sAB[128 + threadIdx.x] + sAB[192 + threadIdx.x];
    partc[(size_t)blockIdx.x * 64 + threadIdx.x] = s;
  }
}

// ---------------- finalize fused-partial stats ----------------
__global__ __launch_bounds__(1024) void finC_k(const float* __restrict__ partc,
                                               const float* __restrict__ g,
                                               const float* __restrict__ bb,
                                               float* __restrict__ sb) {
  __shared__ float red[16 * 64];
  __shared__ float red2[64];
  int ch = threadIdx.x & 63, grp = threadIdx.x >> 6;   // 16 groups x 200 blocks
  float s = 0.f;
  const float* p = partc + (size_t)grp * 200 * 64 + ch;
#pragma unroll 4
  for (int j = 0; j < 200; j++) s += p[(size_t)j * 64];
  red[grp * 64 + ch] = s;
  __syncthreads();
  if (threadIdx.x < 64) {
    float t = 0.f;
#pragma unroll
    for (int k = 0; k < 16; k++) t += red[k * 64 + threadIdx.x];
    red2[threadIdx.x] = t;
  }
  __syncthreads();
  if (threadIdx.x < 32) {
    int co = threadIdx.x;
    float sum = red2[co], sum2 = red2[32 + co];
    const float inv = 1.f / 819200.f;
    float mean = sum * inv;
    float var = sum2 * inv - mean * mean;
    float sc = g[co] * rsqrtf(var + 1e-5f);
    sb[co] = sc;
    sb[32 + co] = bb[co] - mean * sc;
  }
}

// ---------------- fused: H = relu(bn(X) [+ H]); optional stats of a = w1*h ----------------
template <typename TH, bool RES, bool STATS1>
__global__ __launch_bounds__(256) void fuse_k(const float* __restrict__ X,
                                              TH* __restrict__ H,
                                              const float* __restrict__ sb,
                                              const float* __restrict__ w1,
                                              float* __restrict__ partc) {
  __shared__ float sAB[4 * 64];
  int idx = blockIdx.x * 256 + threadIdx.x;      // 819200
  int b = idx / PIX, p = idx - b * PIX;
  size_t base = (size_t)b * CHW + p;
  float h[32];
#pragma unroll
  for (int ci = 0; ci < 32; ci++) {
    float v = X[base + (size_t)ci * PIX];
    v = fmaf(v, sb[ci], sb[32 + ci]);
    if (RES) v += ldH(H, base + (size_t)ci * PIX);
    v = fmaxf(v, 0.f);
    h[ci] = v;
    stH(H, base + (size_t)ci * PIX, v);
  }
  if (STATS1) {
    int lane = threadIdx.x & 63, wv = threadIdx.x >> 6;
#pragma unroll 1
    for (int co = 0; co < 32; co++) {
      float a = 0.f;
#pragma unroll
      for (int ci = 0; ci < 32; ci++) a = fmaf(h[ci], w1[co * 32 + ci], a);
      float r = a, r2 = a * a;
#pragma unroll
      for (int off = 32; off > 0; off >>= 1) { r += __shfl_down(r, off); r2 += __shfl_down(r2, off); }
      if (lane == 0) { sAB[wv * 64 + co] = r; sAB[wv * 64 + 32 + co] = r2; }
    }
    __syncthreads();
    if (threadIdx.x < 64) {
      float s = sAB[threadIdx.x] + sAB[64 + threadIdx.x] + sAB[128 + threadIdx.x] + sAB[192 + threadIdx.x];
      partc[(size_t)blockIdx.x * 64 + threadIdx.x] = s;
    }
  }
}

// ---------------- per-res-block weight prep ----------------
// w1T[ci][co] fp32; wA3 bf16 hi/lo: wA3[((t*4+g)*32+co)*8+j] = bf16(w3[co][g*8+j][t])
// and wA3[9216 + e] = bf16(residual). (k = g*8+j matches mfma A-frag layout.)
__global__ __launch_bounds__(256) void rbtrans_k(const float* __restrict__ w1,
                                                 const float* __restrict__ w3,
                                                 float* __restrict__ w1T,
                                                 unsigned short* __restrict__ wA3) {
  int idx = blockIdx.x * 256 + threadIdx.x;      // 40 blocks -> 10240
  if (idx < 1024) {
    int co = idx >> 5, ci = idx & 31;
    w1T[ci * 32 + co] = w1[co * 32 + ci];
  } else if (idx < 10240) {
    int e = idx - 1024;                           // 9216
    int j = e & 7, co = (e >> 3) & 31, g = (e >> 8) & 3, t = e >> 10;
    int ci = g * 8 + j;
    float w = w3[(co * 32 + ci) * 9 + t];
    unsigned short hi = ftobf16(w);
    float rem = w - bf16tof(hi);
    wA3[e] = hi;
    wA3[9216 + e] = ftobf16(rem);
  }
}

// ---------------- conv3x3 32->32 p1 via MFMA; inline o1 = relu(bn1(w1*h)); fused stats --------
template <typename TH>
__global__ __launch_bounds__(256) void conv3_k(const TH* __restrict__ H,
                                               const float* __restrict__ w1T,
                                               const float* __restrict__ sba,
                                               const unsigned short* __restrict__ wA3,
                                               float* __restrict__ X,
                                               float* __restrict__ partc) {
  __shared__ unsigned int o1s[16 * 330];          // [ci-pair][hpx], pad 330 -> 2-way banks
  __shared__ float sAB[4 * 64];
  int tile_id = blockIdx.x;                       // 25 tiles (5x5 of 16x16)
  int ty0 = (tile_id / 5) * 16, tx0 = (tile_id % 5) * 16;
  int b = blockIdx.y;
  size_t ibase = (size_t)b * CHW;

  // ---- phase 1 ----
  for (int px = threadIdx.x; px < 324; px += 256) {
    int iy = px / 18, ix = px - iy * 18;
    int gy = ty0 - 1 + iy, gx = tx0 - 1 + ix;
    bool inimg = (gy >= 0 && gy < HW_ && gx >= 0 && gx < HW_);
    float a[32];
#pragma unroll
    for (int u = 0; u < 32; u++) a[u] = 0.f;
    if (inimg) {
      size_t hoff = ibase + (size_t)gy * HW_ + gx;
#pragma unroll 4
      for (int cj = 0; cj < 32; cj++) {
        float hv = ldH(H, hoff + (size_t)cj * PIX);
        const float* wr = w1T + cj * 32;
#pragma unroll
        for (int u = 0; u < 32; u++) a[u] = fmaf(hv, wr[u], a[u]);
      }
    }
#pragma unroll
    for (int pr = 0; pr < 16; pr++) {
      // zero-padding applies AFTER bn+relu: out-of-image halo is exactly 0
      float o0 = inimg ? fmaxf(fmaf(a[2 * pr], sba[2 * pr], sba[32 + 2 * pr]), 0.f) : 0.f;
      float o1v = inimg ? fmaxf(fmaf(a[2 * pr + 1], sba[2 * pr + 1], sba[32 + 2 * pr + 1]), 0.f) : 0.f;
      unsigned int pk = (unsigned int)ftobf16(o0) | ((unsigned int)ftobf16(o1v) << 16);
      o1s[pr * 330 + px] = pk;
    }
  }
  __syncthreads();

  // ---- phase 2: MFMA ----
  int lane = threadIdx.x & 63;
  int wid = threadIdx.x >> 6;
  int l15 = lane & 15, lg = lane >> 4;

  f32x4 acc8[8];                                  // unit u = s*2 + Mt; pg = wid*4+s
#pragma unroll
  for (int u = 0; u < 8; u++) acc8[u] = f32x4{0.f, 0.f, 0.f, 0.f};

#pragma unroll 1
  for (int t = 0; t < 9; t++) {
    int dy = t / 3, dx = t - dy * 3;
    int abase = ((t * 4 + lg) * 32 + l15) * 8;    // Mt=0; Mt=1 at +128
    bf16x8 ah0 = *reinterpret_cast<const bf16x8*>(wA3 + abase);
    bf16x8 ah1 = *reinterpret_cast<const bf16x8*>(wA3 + abase + 128);
    bf16x8 al0 = *reinterpret_cast<const bf16x8*>(wA3 + 9216 + abase);
    bf16x8 al1 = *reinterpret_cast<const bf16x8*>(wA3 + 9216 + abase + 128);
#pragma unroll
    for (int s = 0; s < 4; s++) {
      int hpx = (wid * 4 + s + dy) * 18 + l15 + dx;
      int wbase = lg * 4 * 330 + hpx;
      union { unsigned int u[4]; bf16x8 v; } bb;
      bb.u[0] = o1s[wbase];
      bb.u[1] = o1s[wbase + 330];
      bb.u[2] = o1s[wbase + 660];
      bb.u[3] = o1s[wbase + 990];
      acc8[s * 2 + 0] = __builtin_amdgcn_mfma_f32_16x16x32_bf16(ah0, bb.v, acc8[s * 2 + 0], 0, 0, 0);
      acc8[s * 2 + 0] = __builtin_amdgcn_mfma_f32_16x16x32_bf16(al0, bb.v, acc8[s * 2 + 0], 0, 0, 0);
      acc8[s * 2 + 1] = __builtin_amdgcn_mfma_f32_16x16x32_bf16(ah1, bb.v, acc8[s * 2 + 1], 0, 0, 0);
      acc8[s * 2 + 1] = __builtin_amdgcn_mfma_f32_16x16x32_bf16(al1, bb.v, acc8[s * 2 + 1], 0, 0, 0);
    }
  }

  // ---- store + fused bn2 stats ----
  float sacc[2][4], s2acc[2][4];
#pragma unroll
  for (int Mt = 0; Mt < 2; Mt++)
#pragma unroll
    for (int r = 0; r < 4; r++) { sacc[Mt][r] = 0.f; s2acc[Mt][r] = 0.f; }

  int gx = tx0 + l15;
#pragma unroll
  for (int s = 0; s < 4; s++) {
    int gy = ty0 + wid * 4 + s;
#pragma unroll
    for (int Mt = 0; Mt < 2; Mt++) {
#pragma unroll
      for (int r = 0; r < 4; r++) {
        float v = acc8[s * 2 + Mt][r];
        int co = Mt * 16 + lg * 4 + r;
        X[ibase + (size_t)co * PIX + gy * HW_ + gx] = v;
        sacc[Mt][r] += v; s2acc[Mt][r] += v * v;
      }
    }
  }
#pragma unroll
  for (int off = 1; off < 16; off <<= 1) {
#pragma unroll
    for (int Mt = 0; Mt < 2; Mt++)
#pragma unroll
      for (int r = 0; r < 4; r++) {
        sacc[Mt][r] += __shfl_xor(sacc[Mt][r], off);
        s2acc[Mt][r] += __shfl_xor(s2acc[Mt][r], off);
      }
  }
  if (l15 == 0) {
#pragma unroll
    for (int Mt = 0; Mt < 2; Mt++)
#pragma unroll
      for (int r = 0; r < 4; r++) {
        int co = Mt * 16 + lg * 4 + r;
        sAB[wid * 64 + co] = sacc[Mt][r];
        sAB[wid * 64 + 32 + co] = s2acc[Mt][r];
      }
  }
  __syncthreads();
  if (threadIdx.x < 64) {
    float s = sAB[threadIdx.x] + sAB[64 + threadIdx.x] + sAB[128 + threadIdx.x] + sAB[192 + threadIdx.x];
    partc[((size_t)(b * 25 + tile_id)) * 64 + threadIdx.x] = s;
  }
}

// ---------------- pcaps weight transpose ----------------
__global__ __launch_bounds__(256) void wtrans_k(const float* __restrict__ w,
                                                float* __restrict__ wT) {
  int idx = blockIdx.x * 256 + threadIdx.x;      // 331776
  int co = idx / 2592, tap = idx - co * 2592;
  wT[tap * 128 + co] = w[idx];
}

// ---------------- primary caps: 512 threads, 4 ci-quarters + LDS reduce ----------------
// Per (ci,ky): load the 80-px H row ONCE into registers (20x float4),
// then 9 coalesced weight loads + 81 static-index FMAs. 8 waves/block.
template <typename TH>
__global__ __launch_bounds__(512) void pcaps_k(const TH* __restrict__ Hh,
                                               const float* __restrict__ wT,
                                               const float* __restrict__ bias,
                                               float* __restrict__ P) {
  __shared__ float pacc[4 * 128 * 9];             // [ciq][co][ox], 18432 B
  int oy = blockIdx.x, b = blockIdx.y;
  int co = threadIdx.x & 127, ciq = threadIdx.x >> 7;
  float acc[9];
#pragma unroll
  for (int j = 0; j < 9; j++) acc[j] = 0.f;
  size_t ibase = (size_t)b * CHW;
#pragma unroll 1
  for (int cis = 0; cis < 8; cis++) {
    int ci = ciq * 8 + cis;
#pragma unroll 1
    for (int ky = 0; ky < 9; ky++) {
      size_t irow = ibase + (size_t)ci * PIX + (oy * 8 + ky) * HW_;
      float r[80];
#pragma unroll
      for (int q = 0; q < 20; q++) ld4H(Hh, irow + q * 4, r + q * 4);
      const float* wr = wT + (ci * 81 + ky * 9) * 128 + co;
      float wv[9];
#pragma unroll
      for (int kx = 0; kx < 9; kx++) wv[kx] = wr[kx * 128];
#pragma unroll
      for (int kx = 0; kx < 9; kx++) {
#pragma unroll
        for (int ox = 0; ox < 9; ox++)
          acc[ox] = fmaf(r[ox * 8 + kx], wv[kx], acc[ox]);
      }
    }
  }
#pragma unroll
  for (int ox = 0; ox < 9; ox++) pacc[(ciq * 128 + co) * 9 + ox] = acc[ox];
  __syncthreads();
  if (threadIdx.x < 128) {
    int c2 = threadIdx.x;
    float bv = bias[c2];
    int ch = c2 >> 3, k = c2 & 7;
#pragma unroll
    for (int ox = 0; ox < 9; ox++) {
      float s = bv + pacc[c2 * 9 + ox] + pacc[(128 + c2) * 9 + ox] +
                pacc[(256 + c2) * 9 + ox] + pacc[(384 + c2) * 9 + ox];
      int pp = ch * 81 + oy * 9 + ox;
      P[((size_t)b * NPRIM + pp) * 8 + k] = s;
    }
  }
}

// ---------------- u_hat[b][p][cd] = sum_k W[p][cd][k] * P[b][p][k] ----------------
__global__ __launch_bounds__(256) void uhat_k(const float* __restrict__ Pp,
                                              const float* __restrict__ W,
                                              float* __restrict__ UH) {
  int p = blockIdx.x;                             // 1296
  __shared__ __align__(16) float ush[1024];       // [128 b][8 k]
  for (int i = threadIdx.x; i < 1024; i += 256) {
    int b = i >> 3, k = i & 7;
    ush[i] = Pp[((size_t)b * NPRIM + p) * 8 + k];
  }
  int cdq = threadIdx.x & 31, bg = threadIdx.x >> 5;
  float4 w0[5], w1[5];
#pragma unroll
  for (int j = 0; j < 5; j++) {
    const float4* wp = (const float4*)(W + ((size_t)p * 160 + j * 32 + cdq) * 8);
    w0[j] = wp[0]; w1[j] = wp[1];
  }
  __syncthreads();
#pragma unroll 1
  for (int pass = 0; pass < 16; pass++) {
    int b = pass * 8 + bg;
    const float4* up = (const float4*)(ush + b * 8);
    float4 u0 = up[0], u1 = up[1];
#pragma unroll
    for (int j = 0; j < 5; j++) {
      float a = w0[j].x * u0.x + w0[j].y * u0.y + w0[j].z * u0.z + w0[j].w * u0.w +
                w1[j].x * u1.x + w1[j].y * u1.y + w1[j].z * u1.z + w1[j].w * u1.w;
      UH[((size_t)b * NPRIM + p) * 160 + j * 32 + cdq] = a;
    }
  }
}

// ---------------- round-0: s[b][c][d] = 0.1 * sum_p u_hat ----------------
__global__ __launch_bounds__(256) void sred0_k(const float* __restrict__ UH,
                                               float* __restrict__ S) {
  int c = blockIdx.x, b = blockIdx.y;
  int d = threadIdx.x & 15, pg = threadIdx.x >> 4;
  float acc = 0.f;
  for (int p = pg; p < NPRIM; p += 16)
    acc += 0.1f * UH[((size_t)b * NPRIM + p) * 160 + c * 16 + d];
  __shared__ float red[256];
  red[threadIdx.x] = acc;
  __syncthreads();
  for (int st = 128; st >= 16; st >>= 1) {
    if (threadIdx.x < st) red[threadIdx.x] += red[threadIdx.x + st];
    __syncthreads();
  }
  if (threadIdx.x < 16) S[((size_t)b * 10 + c) * 16 + threadIdx.x] = red[threadIdx.x];
}

// ---------------- squash (round 0: S -> V) ----------------
__global__ __launch_bounds__(256) void squash_k(const float* __restrict__ S,
                                                float* __restrict__ V) {
  int idx = blockIdx.x * 256 + threadIdx.x;      // 1280
  if (idx >= 1280) return;
  const float* s = S + (size_t)idx * 16;
  float v[16];
  float n2 = 0.f;
#pragma unroll
  for (int d = 0; d < 16; d++) { v[d] = s[d]; n2 += v[d] * v[d]; }
  float sc = (n2 / (1.f + n2)) / sqrtf(n2 + 1e-9f);
#pragma unroll
  for (int d = 0; d < 16; d++) V[(size_t)idx * 16 + d] = v[d] * sc;
}

// ---------------- fused routing round: agreement + blog + softmax + partial sum -----
template <bool FIRST>
__global__ __launch_bounds__(256) void route_k(const float* __restrict__ UH,
                                               const float* __restrict__ V,
                                               const float* __restrict__ blogin,
                                               float* __restrict__ blogout,
                                               float* __restrict__ SPART) {
  __shared__ float cl[10 * 216];
  __shared__ float vsh[160];
  int seg = blockIdx.x, b = blockIdx.y;
  for (int i = threadIdx.x; i < 160; i += 256) vsh[i] = V[(size_t)b * 160 + i];
  __syncthreads();
  int pl = threadIdx.x;
  if (pl < 216) {
    int p = seg * 216 + pl;
    const float4* uh4 = (const float4*)(UH + ((size_t)b * NPRIM + p) * 160);
    float t[10];
#pragma unroll
    for (int c = 0; c < 10; c++) t[c] = 0.f;
#pragma unroll
    for (int j = 0; j < 40; j++) {
      float4 u = uh4[j];
      int c = j >> 2, d0 = (j & 3) * 4;
      t[c] += u.x * vsh[c * 16 + d0] + u.y * vsh[c * 16 + d0 + 1] +
              u.z * vsh[c * 16 + d0 + 2] + u.w * vsh[c * 16 + d0 + 3];
    }
    if (!FIRST) {
      const float* bi = blogin + ((size_t)b * NPRIM + p) * 10;
#pragma unroll
      for (int c = 0; c < 10; c++) t[c] += bi[c];
    }
    float* bo = blogout + ((size_t)b * NPRIM + p) * 10;
#pragma unroll
    for (int c = 0; c < 10; c++) bo[c] = t[c];
    float mx = -3.4e38f;
#pragma unroll
    for (int c = 0; c < 10; c++) mx = fmaxf(mx, t[c]);
    float sum = 0.f;
    float e[10];
#pragma unroll
    for (int c = 0; c < 10; c++) { e[c] = __expf(t[c] - mx); sum += e[c]; }
    float inv = 1.f / sum;
#pragma unroll
    for (int c = 0; c < 10; c++) cl[c * 216 + pl] = e[c] * inv;
  }
  __syncthreads();
  if (threadIdx.x < 160) {
    int c = threadIdx.x >> 4, d = threadIdx.x & 15;
    const float* uhc = UH + ((size_t)b * NPRIM + seg * 216) * 160 + c * 16 + d;
    float s = 0.f;
#pragma unroll 4
    for (int q = 0; q < 216; q++) s += cl[c * 216 + q] * uhc[(size_t)q * 160];
    SPART[((size_t)b * 6 + seg) * 160 + threadIdx.x] = s;
  }
}

// ---------------- reduce 6 partials + squash; FINAL writes v + lengths ----------------
template <bool FINAL>
__global__ __launch_bounds__(256) void squashred_k(const float* __restrict__ SPART,
                                                   float* __restrict__ V,
                                                   float* __restrict__ out) {
  int b = blockIdx.x;
  int t = threadIdx.x;
  if (t < 160) {
    float s = 0.f;
#pragma unroll
    for (int seg = 0; seg < 6; seg++) s += SPART[((size_t)b * 6 + seg) * 160 + t];
    float n2 = s * s;
#pragma unroll
    for (int off = 1; off < 16; off <<= 1) n2 += __shfl_xor(n2, off);
    float sc = (n2 / (1.f + n2)) / sqrtf(n2 + 1e-9f);
    float v = s * sc;
    if (FINAL) {
      out[(size_t)b * 160 + t] = v;
      if ((t & 15) == 0) out[20480 + b * 10 + (t >> 4)] = sqrtf(n2 * sc * sc + 1e-9f);
    } else {
      V[(size_t)b * 160 + t] = v;
    }
  }
}

// ---------------- host-side orchestration ----------------
template <typename TH>
static void run_all(void* const* d_in, float* ws, float* out, size_t tail0, hipStream_t stream) {
  const float* x        = (const float*)d_in[0];
  const float* conv1_w  = (const float*)d_in[1];
  const float* conv1_b  = (const float*)d_in[2];
  const float* bn1_g    = (const float*)d_in[3];
  const float* bn1_b    = (const float*)d_in[4];
  const float* rb_c1_w  = (const float*)d_in[5];
  const float* rb_bn1_g = (const float*)d_in[6];
  const float* rb_bn1_b = (const float*)d_in[7];
  const float* rb_c2_w  = (const float*)d_in[8];
  const float* rb_bn2_g = (const float*)d_in[9];
  const float* rb_bn2_b = (const float*)d_in[10];
  const float* pcaps_w  = (const float*)d_in[11];
  const float* pcaps_b  = (const float*)d_in[12];
  const float* W_caps   = (const float*)d_in[13];

  float* X    = ws;
  TH*    H    = (TH*)(ws + 26214400);
  float* WT   = ws + tail0;
  float* PART = WT + 331776;      // legacy, unused
  float* SB   = PART + 32768;     // 8 sets x 64
  float* P    = SB + 512;
  float* BLOG = P + 1327104;
  float* S    = BLOG + 1658880;
  float* V    = S + 20480;
  float* UH   = ws;               // overlays dead X
  // trunk-phase overlays
  float* W1T   = P;                                  // 1024 fl
  unsigned short* WA3 = (unsigned short*)(P + 1024); // 18432 ushort
  float* PARTC = BLOG;                               // 3200*64 fl
  // routing-phase overlay (P dead after uhat_k)
  float* SPART = P;                                  // 128*6*160 = 122880 fl

  wtrans_k<<<1296, 256, 0, stream>>>(pcaps_w, WT);
  conv1_k<<<3200, 256, 0, stream>>>(x, conv1_w, conv1_b, X, PARTC);
  finC_k<<<1, 1024, 0, stream>>>(PARTC, bn1_g, bn1_b, SB + 0);
  fuse_k<TH, false, true><<<3200, 256, 0, stream>>>(X, H, SB + 0, rb_c1_w + 0, PARTC);
  finC_k<<<1, 1024, 0, stream>>>(PARTC, rb_bn1_g + 0, rb_bn1_b + 0, SB + 1 * 64);

  for (int i = 0; i < 3; i++) {
    int sa = 1 + 2 * i, sx = 2 + 2 * i;
    rbtrans_k<<<40, 256, 0, stream>>>(rb_c1_w + i * 1024, rb_c2_w + i * 9216, W1T, WA3);
    conv3_k<TH><<<dim3(25, 128), 256, 0, stream>>>(H, W1T, SB + sa * 64, WA3, X, PARTC);
    finC_k<<<1, 1024, 0, stream>>>(PARTC, rb_bn2_g + i * 32, rb_bn2_b + i * 32, SB + sx * 64);
    if (i < 2) {
      fuse_k<TH, true, true><<<3200, 256, 0, stream>>>(X, H, SB + sx * 64,
                                                       rb_c1_w + (i + 1) * 1024, PARTC);
      finC_k<<<1, 1024, 0, stream>>>(PARTC, rb_bn1_g + (i + 1) * 32, rb_bn1_b + (i + 1) * 32,
                                     SB + (sx + 1) * 64);
    } else {
      fuse_k<TH, true, false><<<3200, 256, 0, stream>>>(X, H, SB + sx * 64, nullptr, nullptr);
    }
  }

  pcaps_k<TH><<<dim3(9, 128), 512, 0, stream>>>(H, WT, pcaps_b, P);
  uhat_k<<<1296, 256, 0, stream>>>(P, W_caps, UH);

  // routing: r0 uniform, then two fused rounds
  sred0_k<<<dim3(10, 128), 256, 0, stream>>>(UH, S);
  squash_k<<<5, 256, 0, stream>>>(S, V);
  route_k<true><<<dim3(6, 128), 256, 0, stream>>>(UH, V, nullptr, BLOG, SPART);
  squashred_k<false><<<128, 256, 0, stream>>>(SPART, V, nullptr);
  route_k<false><<<dim3(6, 128), 256, 0, stream>>>(UH, V, BLOG, BLOG, SPART);
  squashred_k<true><<<128, 256, 0, stream>>>(SPART, nullptr, out);
}

extern "C" void kernel_launch(void* const* d_in, const int* in_sizes, int n_in,
                              void* d_out, int out_size, void* d_ws, size_t ws_size,
                              hipStream_t stream) {
  (void)in_sizes; (void)n_in; (void)out_size;
  float* ws = (float*)d_ws;
  float* out = (float*)d_out;
  // fp32-H layout needs (52,428,800 + 3,392,000)*4 = 223,283,200 bytes
  if (ws_size >= 223283200ull) {
    run_all<float>(d_in, ws, out, 52428800, stream);
  } else {
    // bf16-H layout needs (39,321,600 + 3,392,000)*4 = 170,854,400 bytes
    run_all<unsigned short>(d_in, ws, out, 39321600, stream);
  }
}

// Round 9
// 1045.313 us; speedup vs baseline: 1.2639x; 1.2639x over previous
//
#include <hip/hip_runtime.h>
#include <hip/hip_bf16.h>
#include <cstddef>

// ResCapsNet forward, round 9.
// - pcaps_k: r7 kernel body EXACTLY (128 thr, launch_bounds(128), r[80] in regs)
//   but split-K over blockIdx.z (2 ci-halves) -> 2x waves (4.5/SIMD), partials
//   to P (half 0, +bias) and P2=BLOG overlay (half 1). uhat_k sums both.
//   r8 lesson: 512-thr variant made compiler drop r[80] from regs (VGPR 56) and
//   re-issue loads; never disturb the proven codegen, add TLP via the grid.
// - Everything else identical to round 7/8 (passed, absmax 0.0039).
//
// ws layout (fp32-H mode, needs 223,283,200 B; bf16-H fallback if smaller):
//   X @ 0 (26,214,400 fl) | H @ 26,214,400 | tail:
//   WT 331,776 | PART 32,768 (unused) | SB 512 | P 1,327,104 | BLOG 1,658,880 | S | V
//   Overlays: trunk: W1T+WA3 in P, PARTC in BLOG; pcaps: P2 in BLOG;
//   routing: SPART in P (dead post-uhat).

#define B_ 128
#define HW_ 80
#define PIX 6400
#define CHW 204800
#define NPRIM 1296

typedef __attribute__((ext_vector_type(8))) short bf16x8;
typedef __attribute__((ext_vector_type(4))) float f32x4;

// ---- H storage helpers (fp32 or bf16) ----
__device__ inline float ldH(const float* p, size_t i) { return p[i]; }
__device__ inline float ldH(const unsigned short* p, size_t i) {
  union { unsigned int u; float f; } c; c.u = ((unsigned int)p[i]) << 16; return c.f;
}
__device__ inline void stH(float* p, size_t i, float v) { p[i] = v; }
__device__ inline void stH(unsigned short* p, size_t i, float v) {
  __hip_bfloat16 b = __float2bfloat16(v);
  p[i] = *reinterpret_cast<unsigned short*>(&b);
}
__device__ inline float bf16tof(unsigned short u) {
  union { unsigned int uu; float f; } c; c.uu = ((unsigned int)u) << 16; return c.f;
}
__device__ inline unsigned short ftobf16(float v) {
  __hip_bfloat16 b = __float2bfloat16(v);
  return *reinterpret_cast<unsigned short*>(&b);
}
// load 4 consecutive H values into float regs
__device__ inline void ld4H(const float* p, size_t i, float* o) {
  float4 v = *reinterpret_cast<const float4*>(p + i);
  o[0] = v.x; o[1] = v.y; o[2] = v.z; o[3] = v.w;
}
__device__ inline void ld4H(const unsigned short* p, size_t i, float* o) {
  ushort4 v = *reinterpret_cast<const ushort4*>(p + i);
  o[0] = bf16tof(v.x); o[1] = bf16tof(v.y); o[2] = bf16tof(v.z); o[3] = bf16tof(v.w);
}

// ---------------- conv1: 1->32, k3 s1 p1, + bias -> X raw; fused stats ----------------
__global__ __launch_bounds__(256) void conv1_k(const float* __restrict__ x,
                                               const float* __restrict__ w,
                                               const float* __restrict__ bias,
                                               float* __restrict__ out,
                                               float* __restrict__ partc) {
  __shared__ float sAB[4 * 64];
  int idx = blockIdx.x * 256 + threadIdx.x;      // 819200
  int b = idx / PIX, p = idx - b * PIX;
  int y = p / HW_, xx = p - y * HW_;
  const float* xb = x + (size_t)b * PIX;
  float in[3][3];
#pragma unroll
  for (int dy = 0; dy < 3; dy++) {
    int yy = y + dy - 1;
#pragma unroll
    for (int dx = 0; dx < 3; dx++) {
      int xc = xx + dx - 1;
      in[dy][dx] = (yy >= 0 && yy < HW_ && xc >= 0 && xc < HW_) ? xb[yy * HW_ + xc] : 0.f;
    }
  }
  int lane = threadIdx.x & 63, wv = threadIdx.x >> 6;
  size_t obase = (size_t)b * CHW + p;
#pragma unroll 1
  for (int co = 0; co < 32; co++) {
    float a = bias[co];
#pragma unroll
    for (int t = 0; t < 9; t++) a = fmaf(in[t / 3][t % 3], w[co * 9 + t], a);
    out[obase + (size_t)co * PIX] = a;
    float r = a, r2 = a * a;
#pragma unroll
    for (int off = 32; off > 0; off >>= 1) { r += __shfl_down(r, off); r2 += __shfl_down(r2, off); }
    if (lane == 0) { sAB[wv * 64 + co] = r; sAB[wv * 64 + 32 + co] = r2; }
  }
  __syncthreads();
  if (threadIdx.x < 64) {
    float s = sAB[threadIdx.x] + sAB[64 + threadIdx.x] + sAB[128 + threadIdx.x] + sAB[192 + threadIdx.x];
    partc[(size_t)blockIdx.x * 64 + threadIdx.x] = s;
  }
}

// ---------------- finalize fused-partial stats ----------------
__global__ __launch_bounds__(1024) void finC_k(const float* __restrict__ partc,
                                               const float* __restrict__ g,
                                               const float* __restrict__ bb,
                                               float* __restrict__ sb) {
  __shared__ float red[16 * 64];
  __shared__ float red2[64];
  int ch = threadIdx.x & 63, grp = threadIdx.x >> 6;   // 16 groups x 200 blocks
  float s = 0.f;
  const float* p = partc + (size_t)grp * 200 * 64 + ch;
#pragma unroll 4
  for (int j = 0; j < 200; j++) s += p[(size_t)j * 64];
  red[grp * 64 + ch] = s;
  __syncthreads();
  if (threadIdx.x < 64) {
    float t = 0.f;
#pragma unroll
    for (int k = 0; k < 16; k++) t += red[k * 64 + threadIdx.x];
    red2[threadIdx.x] = t;
  }
  __syncthreads();
  if (threadIdx.x < 32) {
    int co = threadIdx.x;
    float sum = red2[co], sum2 = red2[32 + co];
    const float inv = 1.f / 819200.f;
    float mean = sum * inv;
    float var = sum2 * inv - mean * mean;
    float sc = g[co] * rsqrtf(var + 1e-5f);
    sb[co] = sc;
    sb[32 + co] = bb[co] - mean * sc;
  }
}

// ---------------- fused: H = relu(bn(X) [+ H]); optional stats of a = w1*h ----------------
template <typename TH, bool RES, bool STATS1>
__global__ __launch_bounds__(256) void fuse_k(const float* __restrict__ X,
                                              TH* __restrict__ H,
                                              const float* __restrict__ sb,
                                              const float* __restrict__ w1,
                                              float* __restrict__ partc) {
  __shared__ float sAB[4 * 64];
  int idx = blockIdx.x * 256 + threadIdx.x;      // 819200
  int b = idx / PIX, p = idx - b * PIX;
  size_t base = (size_t)b * CHW + p;
  float h[32];
#pragma unroll
  for (int ci = 0; ci < 32; ci++) {
    float v = X[base + (size_t)ci * PIX];
    v = fmaf(v, sb[ci], sb[32 + ci]);
    if (RES) v += ldH(H, base + (size_t)ci * PIX);
    v = fmaxf(v, 0.f);
    h[ci] = v;
    stH(H, base + (size_t)ci * PIX, v);
  }
  if (STATS1) {
    int lane = threadIdx.x & 63, wv = threadIdx.x >> 6;
#pragma unroll 1
    for (int co = 0; co < 32; co++) {
      float a = 0.f;
#pragma unroll
      for (int ci = 0; ci < 32; ci++) a = fmaf(h[ci], w1[co * 32 + ci], a);
      float r = a, r2 = a * a;
#pragma unroll
      for (int off = 32; off > 0; off >>= 1) { r += __shfl_down(r, off); r2 += __shfl_down(r2, off); }
      if (lane == 0) { sAB[wv * 64 + co] = r; sAB[wv * 64 + 32 + co] = r2; }
    }
    __syncthreads();
    if (threadIdx.x < 64) {
      float s = sAB[threadIdx.x] + sAB[64 + threadIdx.x] + sAB[128 + threadIdx.x] + sAB[192 + threadIdx.x];
      partc[(size_t)blockIdx.x * 64 + threadIdx.x] = s;
    }
  }
}

// ---------------- per-res-block weight prep ----------------
// w1T[ci][co] fp32; wA3 bf16 hi/lo: wA3[((t*4+g)*32+co)*8+j] = bf16(w3[co][g*8+j][t])
// and wA3[9216 + e] = bf16(residual). (k = g*8+j matches mfma A-frag layout.)
__global__ __launch_bounds__(256) void rbtrans_k(const float* __restrict__ w1,
                                                 const float* __restrict__ w3,
                                                 float* __restrict__ w1T,
                                                 unsigned short* __restrict__ wA3) {
  int idx = blockIdx.x * 256 + threadIdx.x;      // 40 blocks -> 10240
  if (idx < 1024) {
    int co = idx >> 5, ci = idx & 31;
    w1T[ci * 32 + co] = w1[co * 32 + ci];
  } else if (idx < 10240) {
    int e = idx - 1024;                           // 9216
    int j = e & 7, co = (e >> 3) & 31, g = (e >> 8) & 3, t = e >> 10;
    int ci = g * 8 + j;
    float w = w3[(co * 32 + ci) * 9 + t];
    unsigned short hi = ftobf16(w);
    float rem = w - bf16tof(hi);
    wA3[e] = hi;
    wA3[9216 + e] = ftobf16(rem);
  }
}

// ---------------- conv3x3 32->32 p1 via MFMA; inline o1 = relu(bn1(w1*h)); fused stats --------
template <typename TH>
__global__ __launch_bounds__(256) void conv3_k(const TH* __restrict__ H,
                                               const float* __restrict__ w1T,
                                               const float* __restrict__ sba,
                                               const unsigned short* __restrict__ wA3,
                                               float* __restrict__ X,
                                               float* __restrict__ partc) {
  __shared__ unsigned int o1s[16 * 330];          // [ci-pair][hpx], pad 330 -> 2-way banks
  __shared__ float sAB[4 * 64];
  int tile_id = blockIdx.x;                       // 25 tiles (5x5 of 16x16)
  int ty0 = (tile_id / 5) * 16, tx0 = (tile_id % 5) * 16;
  int b = blockIdx.y;
  size_t ibase = (size_t)b * CHW;

  // ---- phase 1 ----
  for (int px = threadIdx.x; px < 324; px += 256) {
    int iy = px / 18, ix = px - iy * 18;
    int gy = ty0 - 1 + iy, gx = tx0 - 1 + ix;
    bool inimg = (gy >= 0 && gy < HW_ && gx >= 0 && gx < HW_);
    float a[32];
#pragma unroll
    for (int u = 0; u < 32; u++) a[u] = 0.f;
    if (inimg) {
      size_t hoff = ibase + (size_t)gy * HW_ + gx;
#pragma unroll 4
      for (int cj = 0; cj < 32; cj++) {
        float hv = ldH(H, hoff + (size_t)cj * PIX);
        const float* wr = w1T + cj * 32;
#pragma unroll
        for (int u = 0; u < 32; u++) a[u] = fmaf(hv, wr[u], a[u]);
      }
    }
#pragma unroll
    for (int pr = 0; pr < 16; pr++) {
      // zero-padding applies AFTER bn+relu: out-of-image halo is exactly 0
      float o0 = inimg ? fmaxf(fmaf(a[2 * pr], sba[2 * pr], sba[32 + 2 * pr]), 0.f) : 0.f;
      float o1v = inimg ? fmaxf(fmaf(a[2 * pr + 1], sba[2 * pr + 1], sba[32 + 2 * pr + 1]), 0.f) : 0.f;
      unsigned int pk = (unsigned int)ftobf16(o0) | ((unsigned int)ftobf16(o1v) << 16);
      o1s[pr * 330 + px] = pk;
    }
  }
  __syncthreads();

  // ---- phase 2: MFMA ----
  int lane = threadIdx.x & 63;
  int wid = threadIdx.x >> 6;
  int l15 = lane & 15, lg = lane >> 4;

  f32x4 acc8[8];                                  // unit u = s*2 + Mt; pg = wid*4+s
#pragma unroll
  for (int u = 0; u < 8; u++) acc8[u] = f32x4{0.f, 0.f, 0.f, 0.f};

#pragma unroll 1
  for (int t = 0; t < 9; t++) {
    int dy = t / 3, dx = t - dy * 3;
    int abase = ((t * 4 + lg) * 32 + l15) * 8;    // Mt=0; Mt=1 at +128
    bf16x8 ah0 = *reinterpret_cast<const bf16x8*>(wA3 + abase);
    bf16x8 ah1 = *reinterpret_cast<const bf16x8*>(wA3 + abase + 128);
    bf16x8 al0 = *reinterpret_cast<const bf16x8*>(wA3 + 9216 + abase);
    bf16x8 al1 = *reinterpret_cast<const bf16x8*>(wA3 + 9216 + abase + 128);
#pragma unroll
    for (int s = 0; s < 4; s++) {
      int hpx = (wid * 4 + s + dy) * 18 + l15 + dx;
      int wbase = lg * 4 * 330 + hpx;
      union { unsigned int u[4]; bf16x8 v; } bb;
      bb.u[0] = o1s[wbase];
      bb.u[1] = o1s[wbase + 330];
      bb.u[2] = o1s[wbase + 660];
      bb.u[3] = o1s[wbase + 990];
      acc8[s * 2 + 0] = __builtin_amdgcn_mfma_f32_16x16x32_bf16(ah0, bb.v, acc8[s * 2 + 0], 0, 0, 0);
      acc8[s * 2 + 0] = __builtin_amdgcn_mfma_f32_16x16x32_bf16(al0, bb.v, acc8[s * 2 + 0], 0, 0, 0);
      acc8[s * 2 + 1] = __builtin_amdgcn_mfma_f32_16x16x32_bf16(ah1, bb.v, acc8[s * 2 + 1], 0, 0, 0);
      acc8[s * 2 + 1] = __builtin_amdgcn_mfma_f32_16x16x32_bf16(al1, bb.v, acc8[s * 2 + 1], 0, 0, 0);
    }
  }

  // ---- store + fused bn2 stats ----
  float sacc[2][4], s2acc[2][4];
#pragma unroll
  for (int Mt = 0; Mt < 2; Mt++)
#pragma unroll
    for (int r = 0; r < 4; r++) { sacc[Mt][r] = 0.f; s2acc[Mt][r] = 0.f; }

  int gx = tx0 + l15;
#pragma unroll
  for (int s = 0; s < 4; s++) {
    int gy = ty0 + wid * 4 + s;
#pragma unroll
    for (int Mt = 0; Mt < 2; Mt++) {
#pragma unroll
      for (int r = 0; r < 4; r++) {
        float v = acc8[s * 2 + Mt][r];
        int co = Mt * 16 + lg * 4 + r;
        X[ibase + (size_t)co * PIX + gy * HW_ + gx] = v;
        sacc[Mt][r] += v; s2acc[Mt][r] += v * v;
      }
    }
  }
#pragma unroll
  for (int off = 1; off < 16; off <<= 1) {
#pragma unroll
    for (int Mt = 0; Mt < 2; Mt++)
#pragma unroll
      for (int r = 0; r < 4; r++) {
        sacc[Mt][r] += __shfl_xor(sacc[Mt][r], off);
        s2acc[Mt][r] += __shfl_xor(s2acc[Mt][r], off);
      }
  }
  if (l15 == 0) {
#pragma unroll
    for (int Mt = 0; Mt < 2; Mt++)
#pragma unroll
      for (int r = 0; r < 4; r++) {
        int co = Mt * 16 + lg * 4 + r;
        sAB[wid * 64 + co] = sacc[Mt][r];
        sAB[wid * 64 + 32 + co] = s2acc[Mt][r];
      }
  }
  __syncthreads();
  if (threadIdx.x < 64) {
    float s = sAB[threadIdx.x] + sAB[64 + threadIdx.x] + sAB[128 + threadIdx.x] + sAB[192 + threadIdx.x];
    partc[((size_t)(b * 25 + tile_id)) * 64 + threadIdx.x] = s;
  }
}

// ---------------- pcaps weight transpose ----------------
__global__ __launch_bounds__(256) void wtrans_k(const float* __restrict__ w,
                                                float* __restrict__ wT) {
  int idx = blockIdx.x * 256 + threadIdx.x;      // 331776
  int co = idx / 2592, tap = idx - co * 2592;
  wT[tap * 128 + co] = w[idx];
}

// ---------------- primary caps: r7 body, split-K over blockIdx.z (2 ci-halves) --------
// Per (ci,ky): load the 80-px H row ONCE into registers (20x float4),
// then 9 coalesced weight loads + 81 static-index FMAs. Half 0 adds bias.
template <typename TH>
__global__ __launch_bounds__(128) void pcaps_k(const TH* __restrict__ Hh,
                                               const float* __restrict__ wT,
                                               const float* __restrict__ bias,
                                               float* __restrict__ P0,
                                               float* __restrict__ P1) {
  int oy = blockIdx.x, b = blockIdx.y, half = blockIdx.z;
  int co = threadIdx.x;
  int ci0 = half * 16;
  float bv = half ? 0.f : bias[co];
  float acc[9];
#pragma unroll
  for (int j = 0; j < 9; j++) acc[j] = bv;
  size_t ibase = (size_t)b * CHW;
#pragma unroll 1
  for (int cis = 0; cis < 16; cis++) {
    int ci = ci0 + cis;
#pragma unroll 1
    for (int ky = 0; ky < 9; ky++) {
      size_t irow = ibase + (size_t)ci * PIX + (oy * 8 + ky) * HW_;
      float r[80];
#pragma unroll
      for (int q = 0; q < 20; q++) ld4H(Hh, irow + q * 4, r + q * 4);
      const float* wr = wT + (ci * 81 + ky * 9) * 128 + co;
      float wv[9];
#pragma unroll
      for (int kx = 0; kx < 9; kx++) wv[kx] = wr[kx * 128];
#pragma unroll
      for (int kx = 0; kx < 9; kx++) {
#pragma unroll
        for (int ox = 0; ox < 9; ox++)
          acc[ox] = fmaf(r[ox * 8 + kx], wv[kx], acc[ox]);
      }
    }
  }
  float* dst = half ? P1 : P0;
  int ch = co >> 3, k = co & 7;
#pragma unroll
  for (int ox = 0; ox < 9; ox++) {
    int pp = ch * 81 + oy * 9 + ox;
    dst[((size_t)b * NPRIM + pp) * 8 + k] = acc[ox];
  }
}

// ---------------- u_hat[b][p][cd] = sum_k W[p][cd][k] * (P0+P1)[b][p][k] ----------------
__global__ __launch_bounds__(256) void uhat_k(const float* __restrict__ Pa,
                                              const float* __restrict__ Pb,
                                              const float* __restrict__ W,
                                              float* __restrict__ UH) {
  int p = blockIdx.x;                             // 1296
  __shared__ __align__(16) float ush[1024];       // [128 b][8 k]
  for (int i = threadIdx.x; i < 1024; i += 256) {
    int b = i >> 3, k = i & 7;
    size_t off = ((size_t)b * NPRIM + p) * 8 + k;
    ush[i] = Pa[off] + Pb[off];
  }
  int cdq = threadIdx.x & 31, bg = threadIdx.x >> 5;
  float4 w0[5], w1[5];
#pragma unroll
  for (int j = 0; j < 5; j++) {
    const float4* wp = (const float4*)(W + ((size_t)p * 160 + j * 32 + cdq) * 8);
    w0[j] = wp[0]; w1[j] = wp[1];
  }
  __syncthreads();
#pragma unroll 1
  for (int pass = 0; pass < 16; pass++) {
    int b = pass * 8 + bg;
    const float4* up = (const float4*)(ush + b * 8);
    float4 u0 = up[0], u1 = up[1];
#pragma unroll
    for (int j = 0; j < 5; j++) {
      float a = w0[j].x * u0.x + w0[j].y * u0.y + w0[j].z * u0.z + w0[j].w * u0.w +
                w1[j].x * u1.x + w1[j].y * u1.y + w1[j].z * u1.z + w1[j].w * u1.w;
      UH[((size_t)b * NPRIM + p) * 160 + j * 32 + cdq] = a;
    }
  }
}

// ---------------- round-0: s[b][c][d] = 0.1 * sum_p u_hat ----------------
__global__ __launch_bounds__(256) void sred0_k(const float* __restrict__ UH,
                                               float* __restrict__ S) {
  int c = blockIdx.x, b = blockIdx.y;
  int d = threadIdx.x & 15, pg = threadIdx.x >> 4;
  float acc = 0.f;
  for (int p = pg; p < NPRIM; p += 16)
    acc += 0.1f * UH[((size_t)b * NPRIM + p) * 160 + c * 16 + d];
  __shared__ float red[256];
  red[threadIdx.x] = acc;
  __syncthreads();
  for (int st = 128; st >= 16; st >>= 1) {
    if (threadIdx.x < st) red[threadIdx.x] += red[threadIdx.x + st];
    __syncthreads();
  }
  if (threadIdx.x < 16) S[((size_t)b * 10 + c) * 16 + threadIdx.x] = red[threadIdx.x];
}

// ---------------- squash (round 0: S -> V) ----------------
__global__ __launch_bounds__(256) void squash_k(const float* __restrict__ S,
                                                float* __restrict__ V) {
  int idx = blockIdx.x * 256 + threadIdx.x;      // 1280
  if (idx >= 1280) return;
  const float* s = S + (size_t)idx * 16;
  float v[16];
  float n2 = 0.f;
#pragma unroll
  for (int d = 0; d < 16; d++) { v[d] = s[d]; n2 += v[d] * v[d]; }
  float sc = (n2 / (1.f + n2)) / sqrtf(n2 + 1e-9f);
#pragma unroll
  for (int d = 0; d < 16; d++) V[(size_t)idx * 16 + d] = v[d] * sc;
}

// ---------------- fused routing round: agreement + blog + softmax + partial sum -----
template <bool FIRST>
__global__ __launch_bounds__(256) void route_k(const float* __restrict__ UH,
                                               const float* __restrict__ V,
                                               const float* __restrict__ blogin,
                                               float* __restrict__ blogout,
                                               float* __restrict__ SPART) {
  __shared__ float cl[10 * 216];
  __shared__ float vsh[160];
  int seg = blockIdx.x, b = blockIdx.y;
  for (int i = threadIdx.x; i < 160; i += 256) vsh[i] = V[(size_t)b * 160 + i];
  __syncthreads();
  int pl = threadIdx.x;
  if (pl < 216) {
    int p = seg * 216 + pl;
    const float4* uh4 = (const float4*)(UH + ((size_t)b * NPRIM + p) * 160);
    float t[10];
#pragma unroll
    for (int c = 0; c < 10; c++) t[c] = 0.f;
#pragma unroll
    for (int j = 0; j < 40; j++) {
      float4 u = uh4[j];
      int c = j >> 2, d0 = (j & 3) * 4;
      t[c] += u.x * vsh[c * 16 + d0] + u.y * vsh[c * 16 + d0 + 1] +
              u.z * vsh[c * 16 + d0 + 2] + u.w * vsh[c * 16 + d0 + 3];
    }
    if (!FIRST) {
      const float* bi = blogin + ((size_t)b * NPRIM + p) * 10;
#pragma unroll
      for (int c = 0; c < 10; c++) t[c] += bi[c];
    }
    float* bo = blogout + ((size_t)b * NPRIM + p) * 10;
#pragma unroll
    for (int c = 0; c < 10; c++) bo[c] = t[c];
    float mx = -3.4e38f;
#pragma unroll
    for (int c = 0; c < 10; c++) mx = fmaxf(mx, t[c]);
    float sum = 0.f;
    float e[10];
#pragma unroll
    for (int c = 0; c < 10; c++) { e[c] = __expf(t[c] - mx); sum += e[c]; }
    float inv = 1.f / sum;
#pragma unroll
    for (int c = 0; c < 10; c++) cl[c * 216 + pl] = e[c] * inv;
  }
  __syncthreads();
  if (threadIdx.x < 160) {
    int c = threadIdx.x >> 4, d = threadIdx.x & 15;
    const float* uhc = UH + ((size_t)b * NPRIM + seg * 216) * 160 + c * 16 + d;
    float s = 0.f;
#pragma unroll 4
    for (int q = 0; q < 216; q++) s += cl[c * 216 + q] * uhc[(size_t)q * 160];
    SPART[((size_t)b * 6 + seg) * 160 + threadIdx.x] = s;
  }
}

// ---------------- reduce 6 partials + squash; FINAL writes v + lengths ----------------
template <bool FINAL>
__global__ __launch_bounds__(256) void squashred_k(const float* __restrict__ SPART,
                                                   float* __restrict__ V,
                                                   float* __restrict__ out) {
  int b = blockIdx.x;
  int t = threadIdx.x;
  if (t < 160) {
    float s = 0.f;
#pragma unroll
    for (int seg = 0; seg < 6; seg++) s += SPART[((size_t)b * 6 + seg) * 160 + t];
    float n2 = s * s;
#pragma unroll
    for (int off = 1; off < 16; off <<= 1) n2 += __shfl_xor(n2, off);
    float sc = (n2 / (1.f + n2)) / sqrtf(n2 + 1e-9f);
    float v = s * sc;
    if (FINAL) {
      out[(size_t)b * 160 + t] = v;
      if ((t & 15) == 0) out[20480 + b * 10 + (t >> 4)] = sqrtf(n2 * sc * sc + 1e-9f);
    } else {
      V[(size_t)b * 160 + t] = v;
    }
  }
}

// ---------------- host-side orchestration ----------------
template <typename TH>
static void run_all(void* const* d_in, float* ws, float* out, size_t tail0, hipStream_t stream) {
  const float* x        = (const float*)d_in[0];
  const float* conv1_w  = (const float*)d_in[1];
  const float* conv1_b  = (const float*)d_in[2];
  const float* bn1_g    = (const float*)d_in[3];
  const float* bn1_b    = (const float*)d_in[4];
  const float* rb_c1_w  = (const float*)d_in[5];
  const float* rb_bn1_g = (const float*)d_in[6];
  const float* rb_bn1_b = (const float*)d_in[7];
  const float* rb_c2_w  = (const float*)d_in[8];
  const float* rb_bn2_g = (const float*)d_in[9];
  const float* rb_bn2_b = (const float*)d_in[10];
  const float* pcaps_w  = (const float*)d_in[11];
  const float* pcaps_b  = (const float*)d_in[12];
  const float* W_caps   = (const float*)d_in[13];

  float* X    = ws;
  TH*    H    = (TH*)(ws + 26214400);
  float* WT   = ws + tail0;
  float* PART = WT + 331776;      // legacy, unused
  float* SB   = PART + 32768;     // 8 sets x 64
  float* P    = SB + 512;
  float* BLOG = P + 1327104;
  float* S    = BLOG + 1658880;
  float* V    = S + 20480;
  float* UH   = ws;               // overlays dead X
  // trunk-phase overlays
  float* W1T   = P;                                  // 1024 fl
  unsigned short* WA3 = (unsigned short*)(P + 1024); // 18432 ushort
  float* PARTC = BLOG;                               // 3200*64 fl
  // pcaps-phase overlay: second partial-P in BLOG (free between trunk and routing)
  float* P2    = BLOG;                               // 1,327,104 fl
  // routing-phase overlay (P dead after uhat_k)
  float* SPART = P;                                  // 128*6*160 = 122880 fl

  wtrans_k<<<1296, 256, 0, stream>>>(pcaps_w, WT);
  conv1_k<<<3200, 256, 0, stream>>>(x, conv1_w, conv1_b, X, PARTC);
  finC_k<<<1, 1024, 0, stream>>>(PARTC, bn1_g, bn1_b, SB + 0);
  fuse_k<TH, false, true><<<3200, 256, 0, stream>>>(X, H, SB + 0, rb_c1_w + 0, PARTC);
  finC_k<<<1, 1024, 0, stream>>>(PARTC, rb_bn1_g + 0, rb_bn1_b + 0, SB + 1 * 64);

  for (int i = 0; i < 3; i++) {
    int sa = 1 + 2 * i, sx = 2 + 2 * i;
    rbtrans_k<<<40, 256, 0, stream>>>(rb_c1_w + i * 1024, rb_c2_w + i * 9216, W1T, WA3);
    conv3_k<TH><<<dim3(25, 128), 256, 0, stream>>>(H, W1T, SB + sa * 64, WA3, X, PARTC);
    finC_k<<<1, 1024, 0, stream>>>(PARTC, rb_bn2_g + i * 32, rb_bn2_b + i * 32, SB + sx * 64);
    if (i < 2) {
      fuse_k<TH, true, true><<<3200, 256, 0, stream>>>(X, H, SB + sx * 64,
                                                       rb_c1_w + (i + 1) * 1024, PARTC);
      finC_k<<<1, 1024, 0, stream>>>(PARTC, rb_bn1_g + (i + 1) * 32, rb_bn1_b + (i + 1) * 32,
                                     SB + (sx + 1) * 64);
    } else {
      fuse_k<TH, true, false><<<3200, 256, 0, stream>>>(X, H, SB + sx * 64, nullptr, nullptr);
    }
  }

  pcaps_k<TH><<<dim3(9, 128, 2), 128, 0, stream>>>(H, WT, pcaps_b, P, P2);
  uhat_k<<<1296, 256, 0, stream>>>(P, P2, W_caps, UH);

  // routing: r0 uniform, then two fused rounds
  sred0_k<<<dim3(10, 128), 256, 0, stream>>>(UH, S);
  squash_k<<<5, 256, 0, stream>>>(S, V);
  route_k<true><<<dim3(6, 128), 256, 0, stream>>>(UH, V, nullptr, BLOG, SPART);
  squashred_k<false><<<128, 256, 0, stream>>>(SPART, V, nullptr);
  route_k<false><<<dim3(6, 128), 256, 0, stream>>>(UH, V, BLOG, BLOG, SPART);
  squashred_k<true><<<128, 256, 0, stream>>>(SPART, nullptr, out);
}

extern "C" void kernel_launch(void* const* d_in, const int* in_sizes, int n_in,
                              void* d_out, int out_size, void* d_ws, size_t ws_size,
                              hipStream_t stream) {
  (void)in_sizes; (void)n_in; (void)out_size;
  float* ws = (float*)d_ws;
  float* out = (float*)d_out;
  // fp32-H layout needs (52,428,800 + 3,392,000)*4 = 223,283,200 bytes
  if (ws_size >= 223283200ull) {
    run_all<float>(d_in, ws, out, 52428800, stream);
  } else {
    // bf16-H layout needs (39,321,600 + 3,392,000)*4 = 170,854,400 bytes
    run_all<unsigned short>(d_in, ws, out, 39321600, stream);
  }
}